// Round 3
// baseline (348.667 us; speedup 1.0000x reference)
//
#include <hip/hip_runtime.h>
#include <math.h>

#define Nq 2048
#define Bq 8
#define Kq 4
#define BKq 32
#define NL 32  // elements per lane (2048 / 64)
#define TWO_PI_D 6.283185307179586
#define PI_D 3.141592653589793

// ---------------- wave-level helpers (no barriers) ----------------

__device__ __forceinline__ double wave_sum(double v) {
#pragma unroll
  for (int off = 1; off < 64; off <<= 1) v += __shfl_xor(v, off, 64);
  return v;  // identical on all 64 lanes (commutative pairwise sums)
}

// s = opedoub @ p for this wave's row; lane owns global [32*lane, 32*lane+32).
// opedoub = oper^T oper is pentadiagonal with closed-form bands.
__device__ __forceinline__ void pent_stencil(const double* p, double* out,
                                             int lane) {
  double lm1 = __shfl_up(p[NL - 1], 1, 64);  // global i-1 for e=0
  double lm2 = __shfl_up(p[NL - 2], 1, 64);  // global i-2 for e=0
  double rp1 = __shfl_down(p[0], 1, 64);     // global i+1 for e=31
  double rp2 = __shfl_down(p[1], 1, 64);     // global i+2 for e=31
  int ibase = lane * NL;
#pragma unroll
  for (int e = 0; e < NL; ++e) {
    int i = ibase + e;
    double pim1 = (e >= 1) ? p[e - 1] : lm1;
    double pim2 = (e >= 2) ? p[e - 2] : (e == 1 ? lm1 : lm2);
    double pip1 = (e <= NL - 2) ? p[e + 1] : rp1;
    double pip2 = (e <= NL - 3) ? p[e + 2] : (e == NL - 2 ? rp1 : rp2);
    double c_d = (i == 0 || i == Nq - 1) ? 2.0 : 6.0;
    double c_l = (i == 1 || i == Nq - 1) ? -3.0 : -4.0;
    double c_r = (i == 0 || i == Nq - 2) ? -3.0 : -4.0;
    double acc = c_d * p[e];
    acc += (i >= 1) ? c_l * pim1 : 0.0;
    acc += (i >= 2) ? pim2 : 0.0;
    acc += (i <= Nq - 2) ? c_r * pip1 : 0.0;
    acc += (i <= Nq - 3) ? pip2 : 0.0;
    out[e] = acc;
  }
}

// Wave CG on (coef*opedoub + diag(d2)) z = rhs, d2 already includes +1e-6.
// In: x = x0, r = rhs. Out: x = solution. Zero barriers.
template <bool UNIT_DIAG>
__device__ __forceinline__ void cg_wave(double coef,
                                        const double* __restrict__ d2,
                                        double* r, double* x, int lane) {
  double p[NL], Ap[NL];
  // r = rhs - A x0 ; p = r
  pent_stencil(x, Ap, lane);
  double a0 = 0.0, a1 = 0.0;
#pragma unroll
  for (int e = 0; e < NL; ++e) {
    double de = UNIT_DIAG ? (1.0 + 1e-6) : d2[e * 64 + lane];
    double Ax = coef * Ap[e] + de * x[e];
    r[e] -= Ax;
    p[e] = r[e];
    ((e & 1) ? a1 : a0) += r[e] * r[e];
  }
  double rsold = wave_sum(a0 + a1);
  for (int it = 0; it < 30; ++it) {
    pent_stencil(p, Ap, lane);
    double d0 = 0.0, d1 = 0.0;
#pragma unroll
    for (int e = 0; e < NL; ++e) {
      double de = UNIT_DIAG ? (1.0 + 1e-6) : d2[e * 64 + lane];
      Ap[e] = coef * Ap[e] + de * p[e];
      ((e & 1) ? d1 : d0) += p[e] * Ap[e];
    }
    double pAp = wave_sum(d0 + d1);
    double a = rsold / (pAp + 1e-12);
    double s0 = 0.0, s1 = 0.0;
#pragma unroll
    for (int e = 0; e < NL; ++e) {
      x[e] += a * p[e];
      r[e] -= a * Ap[e];
      ((e & 1) ? s1 : s0) += r[e] * r[e];
    }
    double rsnew = wave_sum(s0 + s1);
    if (sqrt(rsnew) < 1e-6) break;  // uniform across lanes; == ref freeze
    double bta = rsnew / (rsold + 1e-12);
#pragma unroll
    for (int e = 0; e < NL; ++e) p[e] = r[e] + bta * p[e];
    rsold = rsnew;
  }
}

__device__ __forceinline__ double blk_reduce(double v, double* sh) {
#pragma unroll
  for (int off = 32; off > 0; off >>= 1) v += __shfl_down(v, off, 64);
  int wid = threadIdx.x >> 6;
  int lane = threadIdx.x & 63;
  __syncthreads();
  if (lane == 0) sh[wid] = v;
  __syncthreads();
  double r = sh[0] + sh[1] + sh[2] + sh[3];
  __syncthreads();
  return r;
}

// ---------------- kernel A: hyperparameter MLP (parallel) ----------------
__global__ __launch_bounds__(512) void hyper_kernel(
    const float* __restrict__ init_freqs, const float* __restrict__ alpha_p,
    const float* __restrict__ beta_p, const int* __restrict__ iter_p,
    const float* __restrict__ fe_w1, const float* __restrict__ fe_b1,
    const float* __restrict__ fe_w2, const float* __restrict__ fe_b2,
    const float* __restrict__ pr_w1, const float* __restrict__ pr_b1,
    const float* __restrict__ pr_w2, const float* __restrict__ pr_b2,
    const float* __restrict__ pr_w3, const float* __restrict__ pr_b3,
    const float* __restrict__ iter_w_p, double* __restrict__ hdr,
    float* __restrict__ out_scal) {
  __shared__ double sh_avg[Bq];
  __shared__ double sh_h1[Bq][32];
  __shared__ double sh_z[Bq][18];
  __shared__ double sh_z1[Bq][64];
  __shared__ double sh_z2[Bq][32];
  __shared__ double sh_res[Bq][2];
  int tid = threadIdx.x;
  double alpha = (double)alpha_p[0], beta = (double)beta_p[0];
  double iter = (double)iter_p[0];

  if (tid < Bq) {
    double avg = 0.0;
#pragma unroll
    for (int k = 0; k < Kq; ++k) avg += (double)init_freqs[tid * Kq + k];
    sh_avg[tid] = avg * (1.0 / Kq);
  }
  __syncthreads();
  if (tid < 256) {
    int b = tid >> 5, j = tid & 31;
    double v = (double)fe_w1[j] * sh_avg[b] + (double)fe_b1[j];
    sh_h1[b][j] = v > 0.0 ? v : 0.0;
  }
  __syncthreads();
  if (tid < 128) {
    int b = tid >> 4, j = tid & 15;
    double acc = (double)fe_b2[j];
    for (int i = 0; i < 32; ++i) acc += (double)fe_w2[j * 32 + i] * sh_h1[b][i];
    sh_z[b][j] = acc > 0.0 ? acc : 0.0;
  }
  if (tid >= 256 && tid < 256 + Bq) {
    sh_z[tid - 256][16] = alpha;
    sh_z[tid - 256][17] = beta;
  }
  __syncthreads();
  {
    int b = tid >> 6, j = tid & 63;
    double acc = (double)pr_b1[j];
    for (int i = 0; i < 18; ++i) acc += (double)pr_w1[j * 18 + i] * sh_z[b][i];
    sh_z1[b][j] = acc > 0.0 ? acc : 0.0;
  }
  __syncthreads();
  if (tid < 256) {
    int b = tid >> 5, j = tid & 31;
    double acc = (double)pr_b2[j];
    for (int i = 0; i < 64; ++i) acc += (double)pr_w2[j * 64 + i] * sh_z1[b][i];
    sh_z2[b][j] = acc > 0.0 ? acc : 0.0;
  }
  __syncthreads();
  if (tid < 16) {
    int b = tid >> 1, c = tid & 1;
    double acc = (double)pr_b3[c];
    for (int i = 0; i < 32; ++i) acc += (double)pr_w3[c * 32 + i] * sh_z2[b][i];
    double fac = 1.0 / (1.0 + exp(-(double)iter_w_p[0] * iter));
    sh_res[b][c] = tanh(acc) * fac * 0.1;
  }
  __syncthreads();
  if (tid == 0) {
    double r0 = 0.0, r1 = 0.0;
    for (int b = 0; b < Bq; ++b) { r0 += sh_res[b][0]; r1 += sh_res[b][1]; }
    double na = alpha + r0 * alpha * (1.0 / Bq);
    na = fmin(fmax(na, 1e-6), 0.01);
    double nb = beta + r1 * beta * (1.0 / Bq);
    nb = fmin(fmax(nb, 1e-6), 0.1);
    double betathr = fmin(pow(10.0, iter / 36.0 - 10.0), nb);
    hdr[0] = na;
    hdr[1] = nb;
    hdr[2] = 2.0 / na;       // coefA
    hdr[3] = 2.0 / betathr;  // coefS
    hdr[4] = 1.0 / na;       // inv_alpha
    out_scal[0] = (float)na;
    out_scal[1] = (float)nb;
  }
}

// ------- kernel B: per-b block, wave-per-row: u + cumtrapz scan + rhs -------
__global__ __launch_bounds__(256) void phase_rhs_kernel(
    const float* __restrict__ s, const float* __restrict__ eIF,
    const float* __restrict__ xm, const float* __restrict__ ym,
    const float* __restrict__ sum_x, const float* __restrict__ sum_y,
    const float* __restrict__ lamuda, const float* __restrict__ fs_p,
    const float* __restrict__ var_p, const double* __restrict__ hdr,
    double* __restrict__ cos_w, double* __restrict__ sin_w,
    double* __restrict__ rhsx_w, double* __restrict__ rhsy_w) {
  int b = blockIdx.x;
  int wave = threadIdx.x >> 6;
  int lane = threadIdx.x & 63;
  int row = b * Kq + wave;
  int bb = b * Nq, base = row * Nq;
  double inva = hdr[4];
  double dx = 1.0 / (double)fs_p[0];

  // eIF row scan (cumtrapz building block)
  double ev[NL], pl[NL];
#pragma unroll
  for (int e = 0; e < NL; ++e) ev[e] = (double)eIF[base + lane * NL + e];
  pl[0] = ev[0];
#pragma unroll
  for (int e = 1; e < NL; ++e) pl[e] = pl[e - 1] + ev[e];
  double T = pl[NL - 1], acc = T;
#pragma unroll
  for (int off = 1; off < 64; off <<= 1) {
    double t = __shfl_up(acc, off, 64);
    if (lane >= off) acc += t;
  }
  double offs = acc - T;  // exclusive lane prefix of totals
  double y0 = __shfl(ev[0], 0, 64);

  // u pieces (each wave recomputes row b identically -> bit-identical u)
  double tv[NL];
  double n0 = 0.0, n1 = 0.0;
#pragma unroll
  for (int e = 0; e < NL; ++e) {
    int gi = bb + lane * NL + e;
    tv[e] = (double)s[gi] - (double)sum_x[gi] - (double)sum_y[gi] -
            (double)lamuda[gi] * inva;
    ((e & 1) ? n1 : n0) += tv[e] * tv[e];
  }
  double nsq = wave_sum(n0 + n1);
  double nn = sqrt(nsq);
  double ee = sqrt((double)Nq * (double)var_p[0]);
  double scale = (nn > ee) ? ee / fmax(nn, 1e-30) : 1.0;
  double oms = 1.0 - scale;  // resid = t*(1-scale) + xm*cos + ym*sin

  double c0 = PI_D * dx;
#pragma unroll
  for (int e = 0; e < NL; ++e) {
    int i = lane * NL + e;
    int idx = base + i;
    double S = offs + pl[e];
    double ph = c0 * (2.0 * S - ev[e] - y0);  // == 2*pi*cumtrapz
    double sv, cv;
    sincos(ph, &sv, &cv);
    double resid = tv[e] * oms + (double)xm[idx] * cv + (double)ym[idx] * sv;
    cos_w[idx] = cv;
    sin_w[idx] = sv;
    rhsx_w[idx] = cv * resid;
    rhsy_w[idx] = sv * resid;
  }
}

// ------- kernel C: wave-per-problem CG for xs (blk 0..31) / ys (32..63) -----
__global__ __launch_bounds__(64) void cg_xy_kernel(
    const double* __restrict__ cos_w, const double* __restrict__ sin_w,
    const double* __restrict__ rhsx_w, const double* __restrict__ rhsy_w,
    const float* __restrict__ xm, const float* __restrict__ ym,
    const double* __restrict__ hdr, double* __restrict__ xs_w,
    double* __restrict__ ys_w) {
  __shared__ double sh_d[Nq];  // d2 = trig^2 + 1e-6, layout [e*64+lane]
  int id = blockIdx.x;
  int base = (id & 31) * Nq;
  bool isY = id >= 32;
  int lane = threadIdx.x;
  double coef = hdr[2];
  const double* trig = (isY ? sin_w : cos_w) + base;
  const double* rh = (isY ? rhsy_w : rhsx_w) + base;
  const float* x0f = (isY ? ym : xm) + base;
  double r[NL], x[NL];
#pragma unroll
  for (int e = 0; e < NL; ++e) {
    int i = lane * NL + e;
    double t = trig[i];
    sh_d[e * 64 + lane] = t * t + 1e-6;  // own-lane slots only: no barrier
    r[e] = rh[i];
    x[e] = (double)x0f[i];
  }
  cg_wave<false>(coef, sh_d, r, x, lane);
  double* outw = (isY ? ys_w : xs_w) + base;
#pragma unroll
  for (int e = 0; e < NL; ++e) outw[lane * NL + e] = x[e];
}

// ------- kernel D: deltaIF + smooth CG + outputs + new-phase contribs -------
__global__ __launch_bounds__(64) void cg_smooth_kernel(
    const double* __restrict__ hdr, const float* __restrict__ eIF,
    const double* __restrict__ xs_w, const double* __restrict__ ys_w,
    const float* __restrict__ xm, const float* __restrict__ ym,
    const int* __restrict__ mode_mask, const float* __restrict__ fs_p,
    float* __restrict__ out_eIF, float* __restrict__ out_xm,
    float* __restrict__ out_ym, double* __restrict__ cx_w,
    double* __restrict__ cy_w) {
  __shared__ double sh_xy[2 * Nq];  // park xs,ys during CG (reg pressure)
  int row = blockIdx.x;
  int base = row * Nq;
  int lane = threadIdx.x;
  double fsv = (double)fs_p[0];
  double invdx = fsv, inv2dx = 0.5 * fsv;

  double xs[NL], ys[NL];
#pragma unroll
  for (int e = 0; e < NL; ++e) {
    xs[e] = xs_w[base + lane * NL + e];
    ys[e] = ys_w[base + lane * NL + e];
  }
  double xl = __shfl_up(xs[NL - 1], 1, 64), xr = __shfl_down(xs[0], 1, 64);
  double yl = __shfl_up(ys[NL - 1], 1, 64), yr = __shfl_down(ys[0], 1, 64);
  double r[NL], x[NL];
#pragma unroll
  for (int e = 0; e < NL; ++e) {
    int i = lane * NL + e;
    double xm1 = (e >= 1) ? xs[e - 1] : xl;
    double xp1 = (e <= NL - 2) ? xs[e + 1] : xr;
    double ym1 = (e >= 1) ? ys[e - 1] : yl;
    double yp1 = (e <= NL - 2) ? ys[e + 1] : yr;
    double xb, yb;
    if (i == 0) {
      xb = (xp1 - xs[e]) * invdx;
      yb = (yp1 - ys[e]) * invdx;
    } else if (i == Nq - 1) {
      xb = (xs[e] - xm1) * invdx;
      yb = (ys[e] - ym1) * invdx;
    } else {
      xb = (xp1 - xm1) * inv2dx;
      yb = (yp1 - ym1) * inv2dx;
    }
    double denom = xs[e] * xs[e] + ys[e] * ys[e] + 1e-12;
    r[e] = (xs[e] * yb - ys[e] * xb) / (denom * TWO_PI_D);
    x[e] = 0.0;
    sh_xy[e * 64 + lane] = xs[e];
    sh_xy[Nq + e * 64 + lane] = ys[e];
  }
  cg_wave<true>(hdr[3], nullptr, r, x, lane);

  bool active = mode_mask[row] != 0;
  double eifn[NL], pl[NL];
#pragma unroll
  for (int e = 0; e < NL; ++e) {
    int i = base + lane * NL + e;
    xs[e] = sh_xy[e * 64 + lane];
    ys[e] = sh_xy[Nq + e * 64 + lane];
    double eifv = (double)eIF[i];
    eifn[e] = active ? (eifv - 0.5 * x[e]) : eifv;
    out_eIF[i] = (float)eifn[e];
    out_xm[i] = active ? (float)xs[e] : xm[i];
    out_ym[i] = active ? (float)ys[e] : ym[i];
  }
  // new_phase scan on eifn
  pl[0] = eifn[0];
#pragma unroll
  for (int e = 1; e < NL; ++e) pl[e] = pl[e - 1] + eifn[e];
  double T = pl[NL - 1], acc = T;
#pragma unroll
  for (int off = 1; off < 64; off <<= 1) {
    double t = __shfl_up(acc, off, 64);
    if (lane >= off) acc += t;
  }
  double offs = acc - T;
  double y0 = __shfl(eifn[0], 0, 64);
  double dx = 1.0 / fsv;
  double c0 = PI_D * dx;
#pragma unroll
  for (int e = 0; e < NL; ++e) {
    int i = base + lane * NL + e;
    double S = offs + pl[e];
    double ph = c0 * (2.0 * S - eifn[e] - y0);
    double sv, cv;
    sincos(ph, &sv, &cv);
    cx_w[i] = active ? xs[e] * cv : 0.0;  // maskf*new_xm*cos(new_phase)
    cy_w[i] = active ? ys[e] * sv : 0.0;
  }
}

// ---------------- kernel E: bsx/bsy sums + u + new lamuda ----------------
__global__ __launch_bounds__(256) void final_kernel(
    const float* __restrict__ s, const float* __restrict__ sum_x,
    const float* __restrict__ sum_y, const float* __restrict__ lamuda,
    const float* __restrict__ var_p, const double* __restrict__ hdr,
    const double* __restrict__ cx_w, const double* __restrict__ cy_w,
    float* __restrict__ out_bsx, float* __restrict__ out_bsy,
    float* __restrict__ out_lam) {
  __shared__ double sh_red[4];
  __shared__ double sh_scale;
  int b = blockIdx.x;
  int bb = b * Nq;
  int tid = threadIdx.x;
  double na = hdr[0], inva = hdr[4];
  double t[8];
  double loc = 0.0;
#pragma unroll
  for (int e = 0; e < 8; ++e) {
    int gi = bb + tid + e * 256;
    t[e] = (double)s[gi] - (double)sum_x[gi] - (double)sum_y[gi] -
           (double)lamuda[gi] * inva;
    loc += t[e] * t[e];
  }
  double nsq = blk_reduce(loc, sh_red);
  if (tid == 0) {
    double n = sqrt(nsq);
    double ee = sqrt((double)Nq * (double)var_p[0]);
    sh_scale = (n > ee) ? ee / fmax(n, 1e-30) : 1.0;
  }
  __syncthreads();
  double scale = sh_scale;
#pragma unroll
  for (int e = 0; e < 8; ++e) {
    int i = tid + e * 256;
    int gi = bb + i;
    double bx = 0.0, by = 0.0;
#pragma unroll
    for (int k = 0; k < Kq; ++k) {
      bx += cx_w[(b * Kq + k) * Nq + i];
      by += cy_w[(b * Kq + k) * Nq + i];
    }
    double u = t[e] * scale;
    double nl = (double)lamuda[gi] + na * (u + bx + by - (double)s[gi]);
    out_bsx[gi] = (float)bx;
    out_bsy[gi] = (float)by;
    out_lam[gi] = (float)nl;
  }
}

// ---------------- launcher ----------------
extern "C" void kernel_launch(void* const* d_in, const int* in_sizes, int n_in,
                              void* d_out, int out_size, void* d_ws, size_t ws_size,
                              hipStream_t stream) {
  (void)in_sizes; (void)n_in; (void)out_size; (void)ws_size;
  const float* s = (const float*)d_in[0];
  const float* eIF = (const float*)d_in[1];
  const float* xm = (const float*)d_in[2];
  const float* ym = (const float*)d_in[3];
  const float* sum_x = (const float*)d_in[4];
  const float* sum_y = (const float*)d_in[5];
  const float* lamuda = (const float*)d_in[6];
  const float* init_freqs = (const float*)d_in[7];
  const int* mode_mask = (const int*)d_in[8];
  const float* alpha = (const float*)d_in[9];
  const float* beta = (const float*)d_in[10];
  const float* var = (const float*)d_in[11];
  const float* fs = (const float*)d_in[12];
  const int* iteration = (const int*)d_in[13];
  const float* fe_w1 = (const float*)d_in[14];
  const float* fe_b1 = (const float*)d_in[15];
  const float* fe_w2 = (const float*)d_in[16];
  const float* fe_b2 = (const float*)d_in[17];
  const float* pr_w1 = (const float*)d_in[18];
  const float* pr_b1 = (const float*)d_in[19];
  const float* pr_w2 = (const float*)d_in[20];
  const float* pr_b2 = (const float*)d_in[21];
  const float* pr_w3 = (const float*)d_in[22];
  const float* pr_b3 = (const float*)d_in[23];
  const float* iter_weight = (const float*)d_in[24];

  float* out = (float*)d_out;
  const int BN = Bq * Nq;      // 16384
  const int BKN = BKq * Nq;    // 65536
  float* out_eIF = out;
  float* out_xm = out + BKN;
  float* out_ym = out + 2 * BKN;
  float* out_bsx = out + 3 * BKN;
  float* out_bsy = out + 3 * BKN + BN;
  float* out_lam = out + 3 * BKN + 2 * BN;
  float* out_scal = out + 3 * BKN + 3 * BN;  // [new_alpha, new_beta]

  double* W = (double*)d_ws;
  double* hdr = W;              // 16
  double* cos_w = W + 16;
  double* sin_w = cos_w + BKN;
  double* rhsx_w = sin_w + BKN;
  double* rhsy_w = rhsx_w + BKN;
  double* xs_w = rhsy_w + BKN;
  double* ys_w = xs_w + BKN;
  double* cx_w = ys_w + BKN;
  double* cy_w = cx_w + BKN;    // total ~4.2 MB

  hyper_kernel<<<1, 512, 0, stream>>>(init_freqs, alpha, beta, iteration, fe_w1,
                                      fe_b1, fe_w2, fe_b2, pr_w1, pr_b1, pr_w2,
                                      pr_b2, pr_w3, pr_b3, iter_weight, hdr,
                                      out_scal);
  phase_rhs_kernel<<<Bq, 256, 0, stream>>>(s, eIF, xm, ym, sum_x, sum_y, lamuda,
                                           fs, var, hdr, cos_w, sin_w, rhsx_w,
                                           rhsy_w);
  cg_xy_kernel<<<2 * BKq, 64, 0, stream>>>(cos_w, sin_w, rhsx_w, rhsy_w, xm, ym,
                                           hdr, xs_w, ys_w);
  cg_smooth_kernel<<<BKq, 64, 0, stream>>>(hdr, eIF, xs_w, ys_w, xm, ym,
                                           mode_mask, fs, out_eIF, out_xm,
                                           out_ym, cx_w, cy_w);
  final_kernel<<<Bq, 256, 0, stream>>>(s, sum_x, sum_y, lamuda, var, hdr, cx_w,
                                       cy_w, out_bsx, out_bsy, out_lam);
}

// Round 4
// 246.097 us; speedup vs baseline: 1.4168x; 1.4168x over previous
//
#include <hip/hip_runtime.h>
#include <math.h>

#define Nq 2048
#define Bq 8
#define Kq 4
#define BKq 32
#define NL 32  // elements per lane (2048 / 64)
#define TWO_PI_D 6.283185307179586
#define PI_D 3.141592653589793

// ---------------- wave-level helpers (no barriers) ----------------

__device__ __forceinline__ double wave_sum(double v) {
#pragma unroll
  for (int off = 1; off < 64; off <<= 1) v += __shfl_xor(v, off, 64);
  return v;
}

__device__ __forceinline__ float wave_sumf(float v) {
#pragma unroll
  for (int off = 1; off < 64; off <<= 1) v += __shfl_xor(v, off, 64);
  return v;
}

// out = opedoub @ p (pentadiagonal closed form), f32, lane owns [32*lane, +32)
__device__ __forceinline__ void pent_stencil_f(const float* p, float* out,
                                               int lane) {
  float lm1 = __shfl_up(p[NL - 1], 1, 64);
  float lm2 = __shfl_up(p[NL - 2], 1, 64);
  float rp1 = __shfl_down(p[0], 1, 64);
  float rp2 = __shfl_down(p[1], 1, 64);
  int ibase = lane * NL;
#pragma unroll
  for (int e = 0; e < NL; ++e) {
    int i = ibase + e;
    float pim1 = (e >= 1) ? p[e - 1] : lm1;
    float pim2 = (e >= 2) ? p[e - 2] : (e == 1 ? lm1 : lm2);
    float pip1 = (e <= NL - 2) ? p[e + 1] : rp1;
    float pip2 = (e <= NL - 3) ? p[e + 2] : (e == NL - 2 ? rp1 : rp2);
    float c_d = (i == 0 || i == Nq - 1) ? 2.0f : 6.0f;
    float c_l = (i == 1 || i == Nq - 1) ? -3.0f : -4.0f;
    float c_r = (i == 0 || i == Nq - 2) ? -3.0f : -4.0f;
    float acc = c_d * p[e];
    acc += (i >= 1) ? c_l * pim1 : 0.0f;
    acc += (i >= 2) ? pim2 : 0.0f;
    acc += (i <= Nq - 2) ? c_r * pip1 : 0.0f;
    acc += (i <= Nq - 3) ? pip2 : 0.0f;
    out[e] = acc;
  }
}

// Wave CG (f32 state, zero barriers, no spills) on
// (coef*opedoub + diag(df)) z = rhs; df already includes +1e-6.
// In: x = x0, r = rhs. Out: x = solution.
template <bool UNIT_DIAG>
__device__ __forceinline__ void cg_wave_f(float coef,
                                          const float* __restrict__ df,
                                          float* r, float* x, int lane) {
  float p[NL], Ap[NL];
  pent_stencil_f(x, Ap, lane);
  float a0 = 0.0f, a1 = 0.0f;
#pragma unroll
  for (int e = 0; e < NL; ++e) {
    float de = UNIT_DIAG ? (1.0f + 1e-6f) : df[e];
    r[e] -= coef * Ap[e] + de * x[e];
    p[e] = r[e];
    ((e & 1) ? a1 : a0) += r[e] * r[e];
  }
  float rsold = wave_sumf(a0 + a1);
  for (int it = 0; it < 30; ++it) {
    pent_stencil_f(p, Ap, lane);
    float d0 = 0.0f, d1 = 0.0f;
#pragma unroll
    for (int e = 0; e < NL; ++e) {
      float de = UNIT_DIAG ? (1.0f + 1e-6f) : df[e];
      Ap[e] = coef * Ap[e] + de * p[e];
      ((e & 1) ? d1 : d0) += p[e] * Ap[e];
    }
    float pAp = wave_sumf(d0 + d1);
    float a = rsold / (pAp + 1e-12f);
    float s0 = 0.0f, s1 = 0.0f;
#pragma unroll
    for (int e = 0; e < NL; ++e) {
      x[e] += a * p[e];
      r[e] -= a * Ap[e];
      ((e & 1) ? s1 : s0) += r[e] * r[e];
    }
    float rsnew = wave_sumf(s0 + s1);
    if (sqrtf(rsnew) < 1e-6f) break;  // uniform; == reference freeze
    float bta = rsnew / (rsold + 1e-12f);
#pragma unroll
    for (int e = 0; e < NL; ++e) p[e] = r[e] + bta * p[e];
    rsold = rsnew;
  }
}

__device__ __forceinline__ double blk_reduce(double v, double* sh) {
#pragma unroll
  for (int off = 32; off > 0; off >>= 1) v += __shfl_down(v, off, 64);
  int wid = threadIdx.x >> 6;
  int lane = threadIdx.x & 63;
  __syncthreads();
  if (lane == 0) sh[wid] = v;
  __syncthreads();
  double r = sh[0] + sh[1] + sh[2] + sh[3];
  __syncthreads();
  return r;
}

// ---------------- kernel A: hyperparameter MLP (parallel) ----------------
__global__ __launch_bounds__(512) void hyper_kernel(
    const float* __restrict__ init_freqs, const float* __restrict__ alpha_p,
    const float* __restrict__ beta_p, const int* __restrict__ iter_p,
    const float* __restrict__ fe_w1, const float* __restrict__ fe_b1,
    const float* __restrict__ fe_w2, const float* __restrict__ fe_b2,
    const float* __restrict__ pr_w1, const float* __restrict__ pr_b1,
    const float* __restrict__ pr_w2, const float* __restrict__ pr_b2,
    const float* __restrict__ pr_w3, const float* __restrict__ pr_b3,
    const float* __restrict__ iter_w_p, double* __restrict__ hdr,
    float* __restrict__ out_scal) {
  __shared__ double sh_avg[Bq];
  __shared__ double sh_h1[Bq][32];
  __shared__ double sh_z[Bq][18];
  __shared__ double sh_z1[Bq][64];
  __shared__ double sh_z2[Bq][32];
  __shared__ double sh_res[Bq][2];
  int tid = threadIdx.x;
  double alpha = (double)alpha_p[0], beta = (double)beta_p[0];
  double iter = (double)iter_p[0];

  if (tid < Bq) {
    double avg = 0.0;
#pragma unroll
    for (int k = 0; k < Kq; ++k) avg += (double)init_freqs[tid * Kq + k];
    sh_avg[tid] = avg * (1.0 / Kq);
  }
  __syncthreads();
  if (tid < 256) {
    int b = tid >> 5, j = tid & 31;
    double v = (double)fe_w1[j] * sh_avg[b] + (double)fe_b1[j];
    sh_h1[b][j] = v > 0.0 ? v : 0.0;
  }
  __syncthreads();
  if (tid < 128) {
    int b = tid >> 4, j = tid & 15;
    double acc = (double)fe_b2[j];
    for (int i = 0; i < 32; ++i) acc += (double)fe_w2[j * 32 + i] * sh_h1[b][i];
    sh_z[b][j] = acc > 0.0 ? acc : 0.0;
  }
  if (tid >= 256 && tid < 256 + Bq) {
    sh_z[tid - 256][16] = alpha;
    sh_z[tid - 256][17] = beta;
  }
  __syncthreads();
  {
    int b = tid >> 6, j = tid & 63;
    double acc = (double)pr_b1[j];
    for (int i = 0; i < 18; ++i) acc += (double)pr_w1[j * 18 + i] * sh_z[b][i];
    sh_z1[b][j] = acc > 0.0 ? acc : 0.0;
  }
  __syncthreads();
  if (tid < 256) {
    int b = tid >> 5, j = tid & 31;
    double acc = (double)pr_b2[j];
    for (int i = 0; i < 64; ++i) acc += (double)pr_w2[j * 64 + i] * sh_z1[b][i];
    sh_z2[b][j] = acc > 0.0 ? acc : 0.0;
  }
  __syncthreads();
  if (tid < 16) {
    int b = tid >> 1, c = tid & 1;
    double acc = (double)pr_b3[c];
    for (int i = 0; i < 32; ++i) acc += (double)pr_w3[c * 32 + i] * sh_z2[b][i];
    double fac = 1.0 / (1.0 + exp(-(double)iter_w_p[0] * iter));
    sh_res[b][c] = tanh(acc) * fac * 0.1;
  }
  __syncthreads();
  if (tid == 0) {
    double r0 = 0.0, r1 = 0.0;
    for (int b = 0; b < Bq; ++b) { r0 += sh_res[b][0]; r1 += sh_res[b][1]; }
    double na = alpha + r0 * alpha * (1.0 / Bq);
    na = fmin(fmax(na, 1e-6), 0.01);
    double nb = beta + r1 * beta * (1.0 / Bq);
    nb = fmin(fmax(nb, 1e-6), 0.1);
    double betathr = fmin(pow(10.0, iter / 36.0 - 10.0), nb);
    hdr[0] = na;
    hdr[1] = nb;
    hdr[2] = 2.0 / na;       // coefA
    hdr[3] = 2.0 / betathr;  // coefS
    hdr[4] = 1.0 / na;       // inv_alpha
    out_scal[0] = (float)na;
    out_scal[1] = (float)nb;
  }
}

// ------- kernel B: per-b block, wave-per-row: u + cumtrapz scan + rhs -------
__global__ __launch_bounds__(256) void phase_rhs_kernel(
    const float* __restrict__ s, const float* __restrict__ eIF,
    const float* __restrict__ xm, const float* __restrict__ ym,
    const float* __restrict__ sum_x, const float* __restrict__ sum_y,
    const float* __restrict__ lamuda, const float* __restrict__ fs_p,
    const float* __restrict__ var_p, const double* __restrict__ hdr,
    float* __restrict__ cos_w, float* __restrict__ sin_w,
    float* __restrict__ rhsx_w, float* __restrict__ rhsy_w) {
  int b = blockIdx.x;
  int wave = threadIdx.x >> 6;
  int lane = threadIdx.x & 63;
  int row = b * Kq + wave;
  int bb = b * Nq, base = row * Nq;
  double inva = hdr[4];
  double dx = 1.0 / (double)fs_p[0];

  double ev[NL], pl[NL];
#pragma unroll
  for (int e = 0; e < NL; ++e) ev[e] = (double)eIF[base + lane * NL + e];
  pl[0] = ev[0];
#pragma unroll
  for (int e = 1; e < NL; ++e) pl[e] = pl[e - 1] + ev[e];
  double T = pl[NL - 1], acc = T;
#pragma unroll
  for (int off = 1; off < 64; off <<= 1) {
    double t = __shfl_up(acc, off, 64);
    if (lane >= off) acc += t;
  }
  double offs = acc - T;  // exclusive lane prefix of totals
  double y0 = __shfl(ev[0], 0, 64);

  double tv[NL];
  double n0 = 0.0, n1 = 0.0;
#pragma unroll
  for (int e = 0; e < NL; ++e) {
    int gi = bb + lane * NL + e;
    tv[e] = (double)s[gi] - (double)sum_x[gi] - (double)sum_y[gi] -
            (double)lamuda[gi] * inva;
    ((e & 1) ? n1 : n0) += tv[e] * tv[e];
  }
  double nsq = wave_sum(n0 + n1);
  double nn = sqrt(nsq);
  double ee = sqrt((double)Nq * (double)var_p[0]);
  double scale = (nn > ee) ? ee / fmax(nn, 1e-30) : 1.0;
  double oms = 1.0 - scale;  // resid = t*(1-scale) + xm*cos + ym*sin

  double c0 = PI_D * dx;
#pragma unroll
  for (int e = 0; e < NL; ++e) {
    int i = lane * NL + e;
    int idx = base + i;
    double S = offs + pl[e];
    double ph = c0 * (2.0 * S - ev[e] - y0);  // == 2*pi*cumtrapz
    double sv, cv;
    sincos(ph, &sv, &cv);
    double resid = tv[e] * oms + (double)xm[idx] * cv + (double)ym[idx] * sv;
    cos_w[idx] = (float)cv;
    sin_w[idx] = (float)sv;
    rhsx_w[idx] = (float)(cv * resid);
    rhsy_w[idx] = (float)(sv * resid);
  }
}

// ------- kernel C: wave-per-problem CG for xs (blk 0..31) / ys (32..63) -----
__global__ __launch_bounds__(64, 1) void cg_xy_kernel(
    const float* __restrict__ cos_w, const float* __restrict__ sin_w,
    const float* __restrict__ rhsx_w, const float* __restrict__ rhsy_w,
    const float* __restrict__ xm, const float* __restrict__ ym,
    const double* __restrict__ hdr, float* __restrict__ xs_w,
    float* __restrict__ ys_w) {
  int id = blockIdx.x;
  int base = (id & 31) * Nq;
  bool isY = id >= 32;
  int lane = threadIdx.x;
  float coef = (float)hdr[2];
  const float* trig = (isY ? sin_w : cos_w) + base;
  const float* rh = (isY ? rhsy_w : rhsx_w) + base;
  const float* x0f = (isY ? ym : xm) + base;
  float df[NL], r[NL], x[NL];
#pragma unroll
  for (int e = 0; e < NL; ++e) {
    int i = lane * NL + e;
    float t = trig[i];
    df[e] = t * t + 1e-6f;
    r[e] = rh[i];
    x[e] = x0f[i];
  }
  cg_wave_f<false>(coef, df, r, x, lane);
  float* outw = (isY ? ys_w : xs_w) + base;
#pragma unroll
  for (int e = 0; e < NL; ++e) outw[lane * NL + e] = x[e];
}

// ------- kernel D: deltaIF + smooth CG + outputs + new-phase contribs -------
__global__ __launch_bounds__(64, 1) void cg_smooth_kernel(
    const double* __restrict__ hdr, const float* __restrict__ eIF,
    const float* __restrict__ xs_w, const float* __restrict__ ys_w,
    const float* __restrict__ xm, const float* __restrict__ ym,
    const int* __restrict__ mode_mask, const float* __restrict__ fs_p,
    float* __restrict__ out_eIF, float* __restrict__ out_xm,
    float* __restrict__ out_ym, double* __restrict__ cx_w,
    double* __restrict__ cy_w) {
  __shared__ float sh_xy[2 * Nq];  // park xs,ys during CG (reg pressure)
  int row = blockIdx.x;
  int base = row * Nq;
  int lane = threadIdx.x;
  float fsv = (float)fs_p[0];
  float invdx = fsv, inv2dx = 0.5f * fsv;

  float xs[NL], ys[NL];
#pragma unroll
  for (int e = 0; e < NL; ++e) {
    xs[e] = xs_w[base + lane * NL + e];
    ys[e] = ys_w[base + lane * NL + e];
  }
  float xl = __shfl_up(xs[NL - 1], 1, 64), xr = __shfl_down(xs[0], 1, 64);
  float yl = __shfl_up(ys[NL - 1], 1, 64), yr = __shfl_down(ys[0], 1, 64);
  float r[NL], x[NL];
#pragma unroll
  for (int e = 0; e < NL; ++e) {
    int i = lane * NL + e;
    float xm1 = (e >= 1) ? xs[e - 1] : xl;
    float xp1 = (e <= NL - 2) ? xs[e + 1] : xr;
    float ym1 = (e >= 1) ? ys[e - 1] : yl;
    float yp1 = (e <= NL - 2) ? ys[e + 1] : yr;
    float xb, yb;
    if (i == 0) {
      xb = (xp1 - xs[e]) * invdx;
      yb = (yp1 - ys[e]) * invdx;
    } else if (i == Nq - 1) {
      xb = (xs[e] - xm1) * invdx;
      yb = (ys[e] - ym1) * invdx;
    } else {
      xb = (xp1 - xm1) * inv2dx;
      yb = (yp1 - ym1) * inv2dx;
    }
    float denom = xs[e] * xs[e] + ys[e] * ys[e] + 1e-12f;
    r[e] = (xs[e] * yb - ys[e] * xb) / (denom * (float)TWO_PI_D);
    x[e] = 0.0f;
    sh_xy[e * 64 + lane] = xs[e];
    sh_xy[Nq + e * 64 + lane] = ys[e];
  }
  cg_wave_f<true>((float)hdr[3], nullptr, r, x, lane);

  bool active = mode_mask[row] != 0;
  double eifn[NL], pl[NL];
#pragma unroll
  for (int e = 0; e < NL; ++e) {
    int i = base + lane * NL + e;
    xs[e] = sh_xy[e * 64 + lane];
    ys[e] = sh_xy[Nq + e * 64 + lane];
    double eifv = (double)eIF[i];
    eifn[e] = active ? (eifv - 0.5 * (double)x[e]) : eifv;
    out_eIF[i] = (float)eifn[e];
    out_xm[i] = active ? xs[e] : xm[i];
    out_ym[i] = active ? ys[e] : ym[i];
  }
  // new_phase scan on eifn (f64)
  pl[0] = eifn[0];
#pragma unroll
  for (int e = 1; e < NL; ++e) pl[e] = pl[e - 1] + eifn[e];
  double T = pl[NL - 1], acc = T;
#pragma unroll
  for (int off = 1; off < 64; off <<= 1) {
    double t = __shfl_up(acc, off, 64);
    if (lane >= off) acc += t;
  }
  double offs = acc - T;
  double y0 = __shfl(eifn[0], 0, 64);
  double dx = 1.0 / (double)fs_p[0];
  double c0 = PI_D * dx;
#pragma unroll
  for (int e = 0; e < NL; ++e) {
    int i = base + lane * NL + e;
    double S = offs + pl[e];
    double ph = c0 * (2.0 * S - eifn[e] - y0);
    double sv, cv;
    sincos(ph, &sv, &cv);
    cx_w[i] = active ? (double)xs[e] * cv : 0.0;
    cy_w[i] = active ? (double)ys[e] * sv : 0.0;
  }
}

// ---------------- kernel E: bsx/bsy sums + u + new lamuda ----------------
__global__ __launch_bounds__(256) void final_kernel(
    const float* __restrict__ s, const float* __restrict__ sum_x,
    const float* __restrict__ sum_y, const float* __restrict__ lamuda,
    const float* __restrict__ var_p, const double* __restrict__ hdr,
    const double* __restrict__ cx_w, const double* __restrict__ cy_w,
    float* __restrict__ out_bsx, float* __restrict__ out_bsy,
    float* __restrict__ out_lam) {
  __shared__ double sh_red[4];
  __shared__ double sh_scale;
  int b = blockIdx.x;
  int bb = b * Nq;
  int tid = threadIdx.x;
  double na = hdr[0], inva = hdr[4];
  double t[8];
  double loc = 0.0;
#pragma unroll
  for (int e = 0; e < 8; ++e) {
    int gi = bb + tid + e * 256;
    t[e] = (double)s[gi] - (double)sum_x[gi] - (double)sum_y[gi] -
           (double)lamuda[gi] * inva;
    loc += t[e] * t[e];
  }
  double nsq = blk_reduce(loc, sh_red);
  if (tid == 0) {
    double n = sqrt(nsq);
    double ee = sqrt((double)Nq * (double)var_p[0]);
    sh_scale = (n > ee) ? ee / fmax(n, 1e-30) : 1.0;
  }
  __syncthreads();
  double scale = sh_scale;
#pragma unroll
  for (int e = 0; e < 8; ++e) {
    int i = tid + e * 256;
    int gi = bb + i;
    double bx = 0.0, by = 0.0;
#pragma unroll
    for (int k = 0; k < Kq; ++k) {
      bx += cx_w[(b * Kq + k) * Nq + i];
      by += cy_w[(b * Kq + k) * Nq + i];
    }
    double u = t[e] * scale;
    double nl = (double)lamuda[gi] + na * (u + bx + by - (double)s[gi]);
    out_bsx[gi] = (float)bx;
    out_bsy[gi] = (float)by;
    out_lam[gi] = (float)nl;
  }
}

// ---------------- launcher ----------------
extern "C" void kernel_launch(void* const* d_in, const int* in_sizes, int n_in,
                              void* d_out, int out_size, void* d_ws, size_t ws_size,
                              hipStream_t stream) {
  (void)in_sizes; (void)n_in; (void)out_size; (void)ws_size;
  const float* s = (const float*)d_in[0];
  const float* eIF = (const float*)d_in[1];
  const float* xm = (const float*)d_in[2];
  const float* ym = (const float*)d_in[3];
  const float* sum_x = (const float*)d_in[4];
  const float* sum_y = (const float*)d_in[5];
  const float* lamuda = (const float*)d_in[6];
  const float* init_freqs = (const float*)d_in[7];
  const int* mode_mask = (const int*)d_in[8];
  const float* alpha = (const float*)d_in[9];
  const float* beta = (const float*)d_in[10];
  const float* var = (const float*)d_in[11];
  const float* fs = (const float*)d_in[12];
  const int* iteration = (const int*)d_in[13];
  const float* fe_w1 = (const float*)d_in[14];
  const float* fe_b1 = (const float*)d_in[15];
  const float* fe_w2 = (const float*)d_in[16];
  const float* fe_b2 = (const float*)d_in[17];
  const float* pr_w1 = (const float*)d_in[18];
  const float* pr_b1 = (const float*)d_in[19];
  const float* pr_w2 = (const float*)d_in[20];
  const float* pr_b2 = (const float*)d_in[21];
  const float* pr_w3 = (const float*)d_in[22];
  const float* pr_b3 = (const float*)d_in[23];
  const float* iter_weight = (const float*)d_in[24];

  float* out = (float*)d_out;
  const int BN = Bq * Nq;      // 16384
  const int BKN = BKq * Nq;    // 65536
  float* out_eIF = out;
  float* out_xm = out + BKN;
  float* out_ym = out + 2 * BKN;
  float* out_bsx = out + 3 * BKN;
  float* out_bsy = out + 3 * BKN + BN;
  float* out_lam = out + 3 * BKN + 2 * BN;
  float* out_scal = out + 3 * BKN + 3 * BN;  // [new_alpha, new_beta]

  double* W = (double*)d_ws;
  double* hdr = W;              // 16 doubles
  double* cx_w = W + 16;        // BKN doubles
  double* cy_w = cx_w + BKN;    // BKN doubles
  float* F = (float*)(cy_w + BKN);
  float* cos_w = F;             // BKN floats each below
  float* sin_w = cos_w + BKN;
  float* rhsx_w = sin_w + BKN;
  float* rhsy_w = rhsx_w + BKN;
  float* xs_w = rhsy_w + BKN;
  float* ys_w = xs_w + BKN;     // total ~2.7 MB

  hyper_kernel<<<1, 512, 0, stream>>>(init_freqs, alpha, beta, iteration, fe_w1,
                                      fe_b1, fe_w2, fe_b2, pr_w1, pr_b1, pr_w2,
                                      pr_b2, pr_w3, pr_b3, iter_weight, hdr,
                                      out_scal);
  phase_rhs_kernel<<<Bq, 256, 0, stream>>>(s, eIF, xm, ym, sum_x, sum_y, lamuda,
                                           fs, var, hdr, cos_w, sin_w, rhsx_w,
                                           rhsy_w);
  cg_xy_kernel<<<2 * BKq, 64, 0, stream>>>(cos_w, sin_w, rhsx_w, rhsy_w, xm, ym,
                                           hdr, xs_w, ys_w);
  cg_smooth_kernel<<<BKq, 64, 0, stream>>>(hdr, eIF, xs_w, ys_w, xm, ym,
                                           mode_mask, fs, out_eIF, out_xm,
                                           out_ym, cx_w, cy_w);
  final_kernel<<<Bq, 256, 0, stream>>>(s, sum_x, sum_y, lamuda, var, hdr, cx_w,
                                       cy_w, out_bsx, out_bsy, out_lam);
}

// Round 5
// 171.838 us; speedup vs baseline: 2.0290x; 1.4321x over previous
//
#include <hip/hip_runtime.h>
#include <math.h>

#define Nq 2048
#define Bq 8
#define Kq 4
#define BKq 32
#define NL 32  // elements per lane (2048 / 64)
#define TWO_PI_D 6.283185307179586
#define PI_D 3.141592653589793
#define INV2PI_D 0.15915494309189535

// ---------------- wave helpers ----------------

__device__ __forceinline__ double wave_sum_d(double v) {
#pragma unroll
  for (int off = 1; off < 64; off <<= 1) v += __shfl_xor(v, off, 64);
  return v;
}

// Canonical GCN DPP wave64 sum (rocPRIM sequence); result broadcast via lane 63.
__device__ __forceinline__ float dpp_sum_f32(float v) {
  v += __int_as_float(__builtin_amdgcn_update_dpp(0, __float_as_int(v), 0x111, 0xf, 0xf, false));  // row_shr:1
  v += __int_as_float(__builtin_amdgcn_update_dpp(0, __float_as_int(v), 0x112, 0xf, 0xf, false));  // row_shr:2
  v += __int_as_float(__builtin_amdgcn_update_dpp(0, __float_as_int(v), 0x114, 0xf, 0xe, false));  // row_shr:4
  v += __int_as_float(__builtin_amdgcn_update_dpp(0, __float_as_int(v), 0x118, 0xf, 0xc, false));  // row_shr:8
  v += __int_as_float(__builtin_amdgcn_update_dpp(0, __float_as_int(v), 0x142, 0xa, 0xf, false));  // row_bcast:15
  v += __int_as_float(__builtin_amdgcn_update_dpp(0, __float_as_int(v), 0x143, 0xc, 0xf, false));  // row_bcast:31
  return __int_as_float(__builtin_amdgcn_readlane(__float_as_int(v), 63));
}

__device__ __forceinline__ double lane_excl_prefix_d(double T, int lane) {
  double acc = T;
#pragma unroll
  for (int off = 1; off < 64; off <<= 1) {
    double t = __shfl_up(acc, off, 64);
    if (lane >= off) acc += t;
  }
  return acc - T;
}

__device__ __forceinline__ void fast_sincos_ph(double ph, float* sn, float* cs) {
  double k = trunc(ph * INV2PI_D);
  float phr = (float)(ph - k * TWO_PI_D);
  __sincosf(phr, sn, cs);
}

// pentadiagonal opedoub = oper^T @ oper, f32; lane owns global [32*lane, +32)
__device__ __forceinline__ void pent_f(const float* p, float* out, int lane) {
  float lm1 = __shfl_up(p[NL - 1], 1, 64);
  float lm2 = __shfl_up(p[NL - 2], 1, 64);
  float rp1 = __shfl_down(p[0], 1, 64);
  float rp2 = __shfl_down(p[1], 1, 64);
#pragma unroll
  for (int e = 0; e < NL; ++e) {
    float m2 = (e >= 2) ? p[e - 2] : (e == 1 ? lm1 : lm2);
    float m1 = (e >= 1) ? p[e - 1] : lm1;
    float q1 = (e <= NL - 2) ? p[e + 1] : rp1;
    float q2 = (e <= NL - 3) ? p[e + 2] : (e == NL - 2 ? rp1 : rp2);
    out[e] = (m2 + q2) - 4.0f * (m1 + q1) + 6.0f * p[e];
  }
  if (lane == 0) {  // global rows 0,1
    out[0] = 2.0f * p[0] - 3.0f * p[1] + p[2];
    out[1] = -3.0f * p[0] + 6.0f * p[1] - 4.0f * p[2] + p[3];
  }
  if (lane == 63) {  // global rows N-2, N-1
    out[NL - 2] = p[NL - 4] - 4.0f * p[NL - 3] + 6.0f * p[NL - 2] - 3.0f * p[NL - 1];
    out[NL - 1] = p[NL - 3] - 3.0f * p[NL - 2] + 2.0f * p[NL - 1];
  }
}

// Wave CG (f32 state, zero barriers) on (coef*opedoub + diag(df)) z = rhs.
// df already includes +1e-6. In: x = x0, r = rhs. Out: x = solution.
template <bool UNIT_DIAG>
__device__ __forceinline__ void cg_wave_f(float coef, const float* df, float* r,
                                          float* x, int lane) {
  float p[NL], Ap[NL];
  pent_f(x, Ap, lane);
  float rs0 = 0.0f;
#pragma unroll
  for (int e = 0; e < NL; ++e) {
    float de = UNIT_DIAG ? (1.0f + 1e-6f) : df[e];
    r[e] -= coef * Ap[e] + de * x[e];
    p[e] = r[e];
    rs0 += r[e] * r[e];
  }
  float rsold = dpp_sum_f32(rs0);
  for (int it = 0; it < 30; ++it) {
    pent_f(p, Ap, lane);
    float pap = 0.0f;
#pragma unroll
    for (int e = 0; e < NL; ++e) {
      float de = UNIT_DIAG ? (1.0f + 1e-6f) : df[e];
      Ap[e] = coef * Ap[e] + de * p[e];
      pap += p[e] * Ap[e];
    }
    pap = dpp_sum_f32(pap);
    float a = rsold / (pap + 1e-12f);
    float rs = 0.0f;
#pragma unroll
    for (int e = 0; e < NL; ++e) {
      x[e] += a * p[e];
      r[e] -= a * Ap[e];
      rs += r[e] * r[e];
    }
    float rsnew = dpp_sum_f32(rs);
    if (sqrtf(rsnew) < 1e-6f) break;  // uniform (SGPR); == reference freeze
    float bta = rsnew / (rsold + 1e-12f);
#pragma unroll
    for (int e = 0; e < NL; ++e) p[e] = r[e] + bta * p[e];
    rsold = rsnew;
  }
}

__device__ __forceinline__ double blk_reduce(double v, double* sh) {
#pragma unroll
  for (int off = 32; off > 0; off >>= 1) v += __shfl_down(v, off, 64);
  int wid = threadIdx.x >> 6;
  int lane = threadIdx.x & 63;
  __syncthreads();
  if (lane == 0) sh[wid] = v;
  __syncthreads();
  double r = sh[0] + sh[1] + sh[2] + sh[3];
  __syncthreads();
  return r;
}

// ---------- mega kernel: one block per (b,k) row; wave0=X system, wave1=Y ----
__global__ __launch_bounds__(128, 1) void row_kernel(
    const float* __restrict__ s, const float* __restrict__ eIF,
    const float* __restrict__ xm, const float* __restrict__ ym,
    const float* __restrict__ sum_x, const float* __restrict__ sum_y,
    const float* __restrict__ lamuda, const float* __restrict__ init_freqs,
    const int* __restrict__ mode_mask, const float* __restrict__ alpha_p,
    const float* __restrict__ beta_p, const float* __restrict__ var_p,
    const float* __restrict__ fs_p, const int* __restrict__ iter_p,
    const float* __restrict__ fe_w1, const float* __restrict__ fe_b1,
    const float* __restrict__ fe_w2, const float* __restrict__ fe_b2,
    const float* __restrict__ pr_w1, const float* __restrict__ pr_b1,
    const float* __restrict__ pr_w2, const float* __restrict__ pr_b2,
    const float* __restrict__ pr_w3, const float* __restrict__ pr_b3,
    const float* __restrict__ iter_w_p, double* __restrict__ hdr,
    float* __restrict__ out_eIF, float* __restrict__ out_xm,
    float* __restrict__ out_ym, float* __restrict__ cx_w,
    float* __restrict__ cy_w, float* __restrict__ out_scal) {
  __shared__ double sh_avg[Bq];
  __shared__ double sh_h1[Bq][32];
  __shared__ double sh_z[Bq][18];
  __shared__ double sh_z1[Bq][64];
  __shared__ double sh_z2[Bq][32];
  __shared__ double sh_res[Bq][2];
  __shared__ double sh_hdr[6];
  __shared__ float sh_xs[Nq], sh_ys[Nq];

  const int tid = threadIdx.x;
  const int wv = tid >> 6, lane = tid & 63;
  const int row = blockIdx.x, b = row >> 2;
  const int bb = b * Nq, base = row * Nq;

  // ---- hyperparameter MLP (redundant per block, f64 deterministic) ----
  double alpha = (double)alpha_p[0], beta = (double)beta_p[0];
  double iterv = (double)iter_p[0];
  if (tid < Bq) {
    double avg = 0.0;
#pragma unroll
    for (int k = 0; k < Kq; ++k) avg += (double)init_freqs[tid * Kq + k];
    sh_avg[tid] = avg * (1.0 / Kq);
  }
  __syncthreads();
  for (int n = tid; n < 256; n += 128) {
    int b2 = n >> 5, j = n & 31;
    double v = (double)fe_w1[j] * sh_avg[b2] + (double)fe_b1[j];
    sh_h1[b2][j] = v > 0.0 ? v : 0.0;
  }
  __syncthreads();
  {
    int b2 = tid >> 4, j = tid & 15;
    double acc = (double)fe_b2[j];
    for (int i = 0; i < 32; ++i) acc += (double)fe_w2[j * 32 + i] * sh_h1[b2][i];
    sh_z[b2][j] = acc > 0.0 ? acc : 0.0;
  }
  if (tid < Bq) {
    sh_z[tid][16] = alpha;
    sh_z[tid][17] = beta;
  }
  __syncthreads();
  for (int n = tid; n < 512; n += 128) {
    int b2 = n >> 6, j = n & 63;
    double acc = (double)pr_b1[j];
    for (int i = 0; i < 18; ++i) acc += (double)pr_w1[j * 18 + i] * sh_z[b2][i];
    sh_z1[b2][j] = acc > 0.0 ? acc : 0.0;
  }
  __syncthreads();
  for (int n = tid; n < 256; n += 128) {
    int b2 = n >> 5, j = n & 31;
    double acc = (double)pr_b2[j];
    for (int i = 0; i < 64; ++i) acc += (double)pr_w2[j * 64 + i] * sh_z1[b2][i];
    sh_z2[b2][j] = acc > 0.0 ? acc : 0.0;
  }
  __syncthreads();
  if (tid < 16) {
    int b2 = tid >> 1, c = tid & 1;
    double acc = (double)pr_b3[c];
    for (int i = 0; i < 32; ++i) acc += (double)pr_w3[c * 32 + i] * sh_z2[b2][i];
    double fac = 1.0 / (1.0 + exp(-(double)iter_w_p[0] * iterv));
    sh_res[b2][c] = tanh(acc) * fac * 0.1;
  }
  __syncthreads();
  if (tid == 0) {
    double r0 = 0.0, r1 = 0.0;
    for (int q = 0; q < Bq; ++q) { r0 += sh_res[q][0]; r1 += sh_res[q][1]; }
    double na = fmin(fmax(alpha + r0 * alpha * (1.0 / Bq), 1e-6), 0.01);
    double nb = fmin(fmax(beta + r1 * beta * (1.0 / Bq), 1e-6), 0.1);
    double betathr = fmin(pow(10.0, iterv / 36.0 - 10.0), nb);
    sh_hdr[0] = na;
    sh_hdr[1] = 2.0 / na;       // coefA
    sh_hdr[2] = 2.0 / betathr;  // coefS
    sh_hdr[3] = 1.0 / na;       // inv_alpha
    hdr[0] = na;                // for final_kernel (identical across blocks)
    hdr[4] = 1.0 / na;
    out_scal[0] = (float)na;
    out_scal[1] = (float)nb;
  }
  __syncthreads();
  const float coefA = (float)sh_hdr[1];
  const float coefS = (float)sh_hdr[2];
  const double inva = sh_hdr[3];

  // ---- u scale for batch b (per-wave redundant, f64) ----
  double tv[NL];
  {
    double n0 = 0.0, n1 = 0.0;
#pragma unroll
    for (int e = 0; e < NL; ++e) {
      int gi = bb + lane * NL + e;
      tv[e] = (double)s[gi] - (double)sum_x[gi] - (double)sum_y[gi] -
              (double)lamuda[gi] * inva;
      ((e & 1) ? n1 : n0) += tv[e] * tv[e];
    }
    double nsq = wave_sum_d(n0 + n1);
    double nn = sqrt(nsq);
    double ee = sqrt((double)Nq * (double)var_p[0]);
    double scale = (nn > ee) ? ee / fmax(nn, 1e-30) : 1.0;
    double oms = 1.0 - scale;  // resid = tv*(1-scale) + xm*cos + ym*sin
#pragma unroll
    for (int e = 0; e < NL; ++e) tv[e] *= oms;
  }

  // ---- eIF cumtrapz phase + trig + per-wave system build ----
  const double dx = 1.0 / (double)fs_p[0];
  const double c0 = PI_D * dx;
  float df[NL], r[NL], x[NL];
  {
    double ev[NL], pl[NL];
#pragma unroll
    for (int e = 0; e < NL; ++e) ev[e] = (double)eIF[base + lane * NL + e];
    pl[0] = ev[0];
#pragma unroll
    for (int e = 1; e < NL; ++e) pl[e] = pl[e - 1] + ev[e];
    double offs = lane_excl_prefix_d(pl[NL - 1], lane);
    double y0 = __shfl(ev[0], 0, 64);
#pragma unroll
    for (int e = 0; e < NL; ++e) {
      int i = lane * NL + e;
      double ph = c0 * (2.0 * (offs + pl[e]) - ev[e] - y0);  // 2*pi*cumtrapz
      float sn, cs;
      fast_sincos_ph(ph, &sn, &cs);
      float xmv = xm[base + i], ymv = ym[base + i];
      double resid = tv[e] + (double)xmv * (double)cs + (double)ymv * (double)sn;
      if (wv == 0) {
        df[e] = cs * cs + 1e-6f;
        r[e] = (float)((double)cs * resid);
        x[e] = xmv;
      } else {
        df[e] = sn * sn + 1e-6f;
        r[e] = (float)((double)sn * resid);
        x[e] = ymv;
      }
    }
  }

  // ---- CG: wave0 solves X system, wave1 solves Y system (parallel) ----
  cg_wave_f<false>(coefA, df, r, x, lane);

  // publish xs/ys
  {
    float* dst = (wv == 0) ? sh_xs : sh_ys;
#pragma unroll
    for (int e = 0; e < NL; ++e) dst[e * 64 + lane] = x[e];
  }
  __syncthreads();

  // ---- deltaIF (both waves identically) ----
  {
    float xs[NL], ys[NL];
#pragma unroll
    for (int e = 0; e < NL; ++e) {
      xs[e] = sh_xs[e * 64 + lane];
      ys[e] = sh_ys[e * 64 + lane];
    }
    float invdx = (float)fs_p[0], inv2dx = 0.5f * invdx;
    float xl = __shfl_up(xs[NL - 1], 1, 64), xr = __shfl_down(xs[0], 1, 64);
    float yl = __shfl_up(ys[NL - 1], 1, 64), yr = __shfl_down(ys[0], 1, 64);
#pragma unroll
    for (int e = 0; e < NL; ++e) {
      int i = lane * NL + e;
      float xm1 = (e >= 1) ? xs[e - 1] : xl;
      float xp1 = (e <= NL - 2) ? xs[e + 1] : xr;
      float ym1 = (e >= 1) ? ys[e - 1] : yl;
      float yp1 = (e <= NL - 2) ? ys[e + 1] : yr;
      float xb, yb;
      if (i == 0) {
        xb = (xp1 - xs[e]) * invdx;
        yb = (yp1 - ys[e]) * invdx;
      } else if (i == Nq - 1) {
        xb = (xs[e] - xm1) * invdx;
        yb = (ys[e] - ym1) * invdx;
      } else {
        xb = (xp1 - xm1) * inv2dx;
        yb = (yp1 - ym1) * inv2dx;
      }
      float denom = xs[e] * xs[e] + ys[e] * ys[e] + 1e-12f;
      r[e] = (xs[e] * yb - ys[e] * xb) / (denom * (float)TWO_PI_D);
      x[e] = 0.0f;
    }
  }

  // ---- smooth CG (both waves redundantly; identical input -> identical) ----
  cg_wave_f<true>(coefS, nullptr, r, x, lane);

  // ---- epilogue: outputs + new-phase contributions ----
  bool active = mode_mask[row] != 0;
  double eifn[NL], pl[NL];
#pragma unroll
  for (int e = 0; e < NL; ++e) {
    int i = base + lane * NL + e;
    double eifv = (double)eIF[i];
    eifn[e] = active ? (eifv - 0.5 * (double)x[e]) : eifv;
  }
  if (wv == 0) {
#pragma unroll
    for (int e = 0; e < NL; ++e) {
      int i = base + lane * NL + e;
      out_eIF[i] = (float)eifn[e];
      out_xm[i] = active ? sh_xs[e * 64 + lane] : xm[i];
    }
  } else {
#pragma unroll
    for (int e = 0; e < NL; ++e) {
      int i = base + lane * NL + e;
      out_ym[i] = active ? sh_ys[e * 64 + lane] : ym[i];
    }
  }
  pl[0] = eifn[0];
#pragma unroll
  for (int e = 1; e < NL; ++e) pl[e] = pl[e - 1] + eifn[e];
  double offs = lane_excl_prefix_d(pl[NL - 1], lane);
  double y0 = __shfl(eifn[0], 0, 64);
#pragma unroll
  for (int e = 0; e < NL; ++e) {
    int i = base + lane * NL + e;
    double ph = c0 * (2.0 * (offs + pl[e]) - eifn[e] - y0);
    float sn, cs;
    fast_sincos_ph(ph, &sn, &cs);
    if (wv == 0)
      cx_w[i] = active ? sh_xs[e * 64 + lane] * cs : 0.0f;
    else
      cy_w[i] = active ? sh_ys[e * 64 + lane] * sn : 0.0f;
  }
}

// ---------------- final: bsx/bsy sums + u + new lamuda ----------------
__global__ __launch_bounds__(256) void final_kernel(
    const float* __restrict__ s, const float* __restrict__ sum_x,
    const float* __restrict__ sum_y, const float* __restrict__ lamuda,
    const float* __restrict__ var_p, const double* __restrict__ hdr,
    const float* __restrict__ cx_w, const float* __restrict__ cy_w,
    float* __restrict__ out_bsx, float* __restrict__ out_bsy,
    float* __restrict__ out_lam) {
  __shared__ double sh_red[4];
  __shared__ double sh_scale;
  int b = blockIdx.x;
  int bb = b * Nq;
  int tid = threadIdx.x;
  double na = hdr[0], inva = hdr[4];
  double t[8];
  double loc = 0.0;
#pragma unroll
  for (int e = 0; e < 8; ++e) {
    int gi = bb + tid + e * 256;
    t[e] = (double)s[gi] - (double)sum_x[gi] - (double)sum_y[gi] -
           (double)lamuda[gi] * inva;
    loc += t[e] * t[e];
  }
  double nsq = blk_reduce(loc, sh_red);
  if (tid == 0) {
    double n = sqrt(nsq);
    double ee = sqrt((double)Nq * (double)var_p[0]);
    sh_scale = (n > ee) ? ee / fmax(n, 1e-30) : 1.0;
  }
  __syncthreads();
  double scale = sh_scale;
#pragma unroll
  for (int e = 0; e < 8; ++e) {
    int i = tid + e * 256;
    int gi = bb + i;
    double bx = 0.0, by = 0.0;
#pragma unroll
    for (int k = 0; k < Kq; ++k) {
      bx += (double)cx_w[(b * Kq + k) * Nq + i];
      by += (double)cy_w[(b * Kq + k) * Nq + i];
    }
    double u = t[e] * scale;
    double nl = (double)lamuda[gi] + na * (u + bx + by - (double)s[gi]);
    out_bsx[gi] = (float)bx;
    out_bsy[gi] = (float)by;
    out_lam[gi] = (float)nl;
  }
}

// ---------------- launcher ----------------
extern "C" void kernel_launch(void* const* d_in, const int* in_sizes, int n_in,
                              void* d_out, int out_size, void* d_ws, size_t ws_size,
                              hipStream_t stream) {
  (void)in_sizes; (void)n_in; (void)out_size; (void)ws_size;
  const float* s = (const float*)d_in[0];
  const float* eIF = (const float*)d_in[1];
  const float* xm = (const float*)d_in[2];
  const float* ym = (const float*)d_in[3];
  const float* sum_x = (const float*)d_in[4];
  const float* sum_y = (const float*)d_in[5];
  const float* lamuda = (const float*)d_in[6];
  const float* init_freqs = (const float*)d_in[7];
  const int* mode_mask = (const int*)d_in[8];
  const float* alpha = (const float*)d_in[9];
  const float* beta = (const float*)d_in[10];
  const float* var = (const float*)d_in[11];
  const float* fs = (const float*)d_in[12];
  const int* iteration = (const int*)d_in[13];
  const float* fe_w1 = (const float*)d_in[14];
  const float* fe_b1 = (const float*)d_in[15];
  const float* fe_w2 = (const float*)d_in[16];
  const float* fe_b2 = (const float*)d_in[17];
  const float* pr_w1 = (const float*)d_in[18];
  const float* pr_b1 = (const float*)d_in[19];
  const float* pr_w2 = (const float*)d_in[20];
  const float* pr_b2 = (const float*)d_in[21];
  const float* pr_w3 = (const float*)d_in[22];
  const float* pr_b3 = (const float*)d_in[23];
  const float* iter_weight = (const float*)d_in[24];

  float* out = (float*)d_out;
  const int BN = Bq * Nq;      // 16384
  const int BKN = BKq * Nq;    // 65536
  float* out_eIF = out;
  float* out_xm = out + BKN;
  float* out_ym = out + 2 * BKN;
  float* out_bsx = out + 3 * BKN;
  float* out_bsy = out + 3 * BKN + BN;
  float* out_lam = out + 3 * BKN + 2 * BN;
  float* out_scal = out + 3 * BKN + 3 * BN;  // [new_alpha, new_beta]

  double* W = (double*)d_ws;
  double* hdr = W;                   // 16 doubles
  float* F = (float*)(W + 16);
  float* cx_w = F;                   // BKN floats
  float* cy_w = F + BKN;             // BKN floats

  row_kernel<<<BKq, 128, 0, stream>>>(
      s, eIF, xm, ym, sum_x, sum_y, lamuda, init_freqs, mode_mask, alpha, beta,
      var, fs, iteration, fe_w1, fe_b1, fe_w2, fe_b2, pr_w1, pr_b1, pr_w2,
      pr_b2, pr_w3, pr_b3, iter_weight, hdr, out_eIF, out_xm, out_ym, cx_w,
      cy_w, out_scal);
  final_kernel<<<Bq, 256, 0, stream>>>(s, sum_x, sum_y, lamuda, var, hdr, cx_w,
                                       cy_w, out_bsx, out_bsy, out_lam);
}